// Round 6
// baseline (510.816 us; speedup 1.0000x reference)
//
#include <hip/hip_runtime.h>
#include <stdint.h>
#include <math.h>

// Problem constants (B=4,S=2048 -> T=8192; H=1024; 2H=2048; E=8; K=2)
#define T_TOK 8192
#define H_DIM 1024
#define H2    2048
#define NE    8

typedef unsigned short u16;
typedef __attribute__((ext_vector_type(8))) short bf16x8;   // 8 bf16 in 4 VGPRs
typedef __attribute__((ext_vector_type(4))) float f32x4;    // MFMA 16x16 C/D

__device__ __forceinline__ u16 f32_to_bf16(float f) {
  union { float f; unsigned u; } c; c.f = f;
  unsigned u = c.u + 0x7fffu + ((c.u >> 16) & 1u);  // RNE
  return (u16)(u >> 16);
}
__device__ __forceinline__ float bf2f(u16 v) {
  union { unsigned u; float f; } c; c.u = (unsigned)v << 16; return c.f;
}

// fast gelu (tanh form), |err| vs exact erf-gelu <= ~1e-3 (passed R4/R5,
// absmax unchanged at 1.56e-2)
__device__ __forceinline__ float fast_gelu(float v) {
  float u = v * v;
  float z2 = v * fmaf(u, 0.1029437f, 2.3022078f);
  float e = __builtin_amdgcn_exp2f(z2);
  float r = __builtin_amdgcn_rcpf(1.0f + e);
  return v - v * r;
}

// async global->LDS, 16B per lane. LDS dest is wave-uniform base + lane*16;
// global address is per-lane (exploited for the XOR bank swizzle).
__device__ __forceinline__ void g2l16(const void* g, void* l) {
  __builtin_amdgcn_global_load_lds(
      (const __attribute__((address_space(1))) unsigned*)g,
      (__attribute__((address_space(3))) unsigned*)l, 16, 0, 0);
}

// exclusive prefix of 8 counts, computed per-block (replaces prefix kernel)
__device__ __forceinline__ int prefix_base(const int* counts, int e) {
  int b = 0;
#pragma unroll
  for (int j = 0; j < NE; j++) b += (j < e) ? counts[j] : 0;
  return b;
}

// ---------------- Router (blocks 0..2047) + w1 cvt (blocks 2048..3583).
// w2 cvt moved into g1's grid (R5 post-mortem: serial-chain reduction).
__global__ __launch_bounds__(256) void router_kernel(
    const float* __restrict__ x, const float* __restrict__ rw,
    const float* __restrict__ w1,
    u16* __restrict__ xb, u16* __restrict__ w1b,
    int* __restrict__ tope, float2* __restrict__ gate2) {
  int blk = blockIdx.x;
  if (blk < T_TOK / 4) {
    // one wave per token, fp64 logits (exact products -> ranking matches ref)
    int wave = threadIdx.x >> 6;
    int lane = threadIdx.x & 63;
    int t = blk * 4 + wave;
    const float4* x4 = (const float4*)(x + (size_t)t * H_DIM);
    const float4* rw4 = (const float4*)rw;
    u16* xbrow = xb + (size_t)t * H_DIM;

    double acc[NE];
#pragma unroll
    for (int e = 0; e < NE; e++) acc[e] = 0.0;
#pragma unroll
    for (int i = 0; i < 4; i++) {
      int c = lane + 64 * i;
      float4 xv = x4[c];
      ushort4 bv = make_ushort4(f32_to_bf16(xv.x), f32_to_bf16(xv.y),
                                f32_to_bf16(xv.z), f32_to_bf16(xv.w));
      *(ushort4*)(xbrow + c * 4) = bv;
#pragma unroll
      for (int e = 0; e < NE; e++) {
        float4 wv = rw4[e * 256 + c];
        acc[e] += (double)xv.x * wv.x + (double)xv.y * wv.y +
                  (double)xv.z * wv.z + (double)xv.w * wv.w;
      }
    }
#pragma unroll
    for (int off = 32; off >= 1; off >>= 1)
#pragma unroll
      for (int e = 0; e < NE; e++) acc[e] += __shfl_xor(acc[e], off, 64);

    if (lane == 0) {
      int e0 = 0; double v0 = acc[0];
#pragma unroll
      for (int e = 1; e < NE; e++) if (acc[e] > v0) { v0 = acc[e]; e0 = e; }
      int e1 = -1; double v1 = -1e300;
#pragma unroll
      for (int e = 0; e < NE; e++) if (e != e0 && acc[e] > v1) { v1 = acc[e]; e1 = e; }
      double ex = exp(v1 - v0);
      tope[t] = e0 | (e1 << 8);
      gate2[t] = make_float2((float)(1.0 / (1.0 + ex)), (float)(ex / (1.0 + ex)));
    }
  } else {
    // w1 cvt: 1536 blocks
    int cb = blk - T_TOK / 4;
    const int n4 = NE * H2 * H_DIM / 4;       // 4,194,304 float4s
    const int stride = 1536 * 256;
    const float4* s4 = (const float4*)w1;
    for (int i = cb * 256 + threadIdx.x; i < n4; i += stride) {
      float4 v = s4[i];
      *(ushort4*)(w1b + (size_t)i * 4) = make_ushort4(
          f32_to_bf16(v.x), f32_to_bf16(v.y), f32_to_bf16(v.z), f32_to_bf16(v.w));
    }
  }
}

// ---------------- Build expert lists: counting sort over 8 bins.
__global__ __launch_bounds__(256) void build_kernel(
    const int* __restrict__ tope, int* __restrict__ counts,
    int* __restrict__ tok_list, int2* __restrict__ pos2) {
  __shared__ int cts[4][NE];
  __shared__ int gbase[NE];
  int tid = threadIdx.x, lane = tid & 63, w = tid >> 6;
  int t = blockIdx.x * 256 + tid;
  int pk = tope[t];
  int e0 = pk & 0xff, e1 = (pk >> 8) & 0xff;
  unsigned long long lt = ((unsigned long long)1 << lane) - 1;

  int r0 = 0, r1 = 0;
#pragma unroll
  for (int e = 0; e < NE; e++) {
    unsigned long long b0 = __ballot(e0 == e);
    unsigned long long b1 = __ballot(e1 == e);
    int n0 = __popcll(b0), n1 = __popcll(b1);
    if (e0 == e) r0 = __popcll(b0 & lt);
    if (e1 == e) r1 = n0 + __popcll(b1 & lt);
    if (lane == 0) cts[w][e] = n0 + n1;
  }
  __syncthreads();
  if (tid < NE) {
    int bt = cts[0][tid] + cts[1][tid] + cts[2][tid] + cts[3][tid];
    gbase[tid] = atomicAdd(&counts[tid], bt);
  }
  __syncthreads();
  int off0 = gbase[e0] + r0;
  int off1 = gbase[e1] + r1;
#pragma unroll
  for (int wp = 0; wp < 4; wp++) {
    if (wp < w) { off0 += cts[wp][e0]; off1 += cts[wp][e1]; }
  }
  tok_list[e0 * T_TOK + off0] = t;
  tok_list[e1 * T_TOK + off1] = t;
  pos2[t] = make_int2(off0, off1);
}

// ---------------- G1: w2 cvt (blocks 0..1535) + GEMM (blocks 1536..9727)
// GEMM: h[base+i] = gelu( x[tok_i] @ w1[e]^T ), 128x128 tile, BK=64,
// XOR bank swizzle (R5: conflicts = 0). Block index XCD-swizzled:
// idx = gn*512 + gm so all 16 n-tiles of one m-tile share idx%8 -> same XCD
// L2 caches the A-tile once.
__global__ __launch_bounds__(256) void g1_kernel(
    const u16* __restrict__ xb, const u16* __restrict__ w1b,
    const float* __restrict__ w2, u16* __restrict__ w2b,
    u16* __restrict__ h, const int* __restrict__ tok_list,
    const int* __restrict__ counts) {
  if (blockIdx.x < 1536) {
    // w2 cvt (needed only by g2; rides in g1's spare HBM bandwidth)
    int cb = blockIdx.x;
    const int n4 = NE * H_DIM * H2 / 4;
    const int stride = 1536 * 256;
    const float4* s4 = (const float4*)w2;
    for (int i = cb * 256 + threadIdx.x; i < n4; i += stride) {
      float4 v = s4[i];
      *(ushort4*)(w2b + (size_t)i * 4) = make_ushort4(
          f32_to_bf16(v.x), f32_to_bf16(v.y), f32_to_bf16(v.z), f32_to_bf16(v.w));
    }
    return;
  }
  int i = blockIdx.x - 1536;
  int gn = i >> 9;          // n-tile 0..15
  int gm = i & 511;         // e*64 + mt
  int e = gm >> 6, mt = gm & 63, nt = gn;
  int cnt = counts[e];
  int m0 = mt * 128;
  if (m0 >= cnt) return;
  int base = prefix_base(counts, e);

  __shared__ u16 As[128 * 64];   // 16 KB
  __shared__ u16 Bs[128 * 64];   // 16 KB

  int tid = threadIdx.x;
  int lane = tid & 63, wave = tid >> 6;
  int wr = wave >> 1, wc = wave & 1;
  int quad = lane >> 4, l16 = lane & 15;
  int srow = tid >> 3;                         // staging: 32 rows/round
  int cg = (tid & 7) ^ (srow & 7);             // XOR-swizzled fetch chunk

  const u16* w1e = w1b + (size_t)e * H2 * H_DIM;
  const u16* ap[4]; const u16* bp[4];
#pragma unroll
  for (int R = 0; R < 4; R++) {
    int r = m0 + R * 32 + srow; if (r > cnt - 1) r = cnt - 1;
    ap[R] = xb + (size_t)tok_list[e * T_TOK + r] * H_DIM + cg * 8;
    bp[R] = w1e + (size_t)(nt * 128 + R * 32 + srow) * H_DIM + cg * 8;
  }

  f32x4 acc[4][4];
#pragma unroll
  for (int i2 = 0; i2 < 4; i2++)
#pragma unroll
    for (int j = 0; j < 4; j++)
#pragma unroll
      for (int r = 0; r < 4; r++) acc[i2][j][r] = 0.f;

  int swz = l16 & 7;
  for (int k0 = 0; k0 < H_DIM; k0 += 64) {
#pragma unroll
    for (int R = 0; R < 4; R++) {
      g2l16(ap[R] + k0, As + R * 2048 + tid * 8);
      g2l16(bp[R] + k0, Bs + R * 2048 + tid * 8);
    }
    __syncthreads();
#pragma unroll
    for (int kk = 0; kk < 2; kk++) {
      bf16x8 af[4], bfr[4];
      int q = kk * 4 + quad;
#pragma unroll
      for (int mi = 0; mi < 4; mi++)
        af[mi] = *(const bf16x8*)(As + (wr * 64 + mi * 16 + l16) * 64 + ((q ^ swz) * 8));
#pragma unroll
      for (int ni = 0; ni < 4; ni++)
        bfr[ni] = *(const bf16x8*)(Bs + (wc * 64 + ni * 16 + l16) * 64 + ((q ^ swz) * 8));
#pragma unroll
      for (int mi = 0; mi < 4; mi++)
#pragma unroll
        for (int ni = 0; ni < 4; ni++)
          acc[mi][ni] = __builtin_amdgcn_mfma_f32_16x16x32_bf16(af[mi], bfr[ni], acc[mi][ni], 0, 0, 0);
    }
    __syncthreads();
  }

  // epilogue: fast gelu, store bf16; C/D layout col=lane&15, row=quad*4+reg
#pragma unroll
  for (int mi = 0; mi < 4; mi++) {
    int rbase = wr * 64 + mi * 16 + quad * 4;
#pragma unroll
    for (int r = 0; r < 4; r++) {
      int rr = m0 + rbase + r;
      if (rr < cnt) {
        size_t ho = (size_t)(base + rr) * H2 + nt * 128 + wc * 64 + l16;
#pragma unroll
        for (int ni = 0; ni < 4; ni++)
          h[ho + ni * 16] = f32_to_bf16(fast_gelu(acc[mi][ni][r]));
      }
    }
  }
}

// ---------------- G2: y[base+i] = h[base+i] @ w2[e]^T (BK=64, swizzled,
// XCD-swizzled block index: idx = gn*512 + gm)
__global__ __launch_bounds__(256) void g2_kernel(
    const u16* __restrict__ h, const u16* __restrict__ w2b,
    u16* __restrict__ y, const int* __restrict__ counts) {
  int i = blockIdx.x;
  int gn = i >> 9;          // n-tile 0..7
  int gm = i & 511;         // e*64 + mt
  int e = gm >> 6, mt = gm & 63, nt = gn;
  int cnt = counts[e];
  int m0 = mt * 128;
  if (m0 >= cnt) return;
  int base = prefix_base(counts, e);

  __shared__ u16 As[128 * 64];
  __shared__ u16 Bs[128 * 64];

  int tid = threadIdx.x;
  int lane = tid & 63, wave = tid >> 6;
  int wr = wave >> 1, wc = wave & 1;
  int quad = lane >> 4, l16 = lane & 15;
  int srow = tid >> 3;
  int cg = (tid & 7) ^ (srow & 7);

  const u16* w2e = w2b + (size_t)e * H_DIM * H2;
  const u16* ap[4]; const u16* bp[4];
#pragma unroll
  for (int R = 0; R < 4; R++) {
    int r = m0 + R * 32 + srow; if (r > cnt - 1) r = cnt - 1;
    ap[R] = h + (size_t)(base + r) * H2 + cg * 8;
    bp[R] = w2e + (size_t)(nt * 128 + R * 32 + srow) * H2 + cg * 8;
  }

  f32x4 acc[4][4];
#pragma unroll
  for (int i2 = 0; i2 < 4; i2++)
#pragma unroll
    for (int j = 0; j < 4; j++)
#pragma unroll
      for (int r = 0; r < 4; r++) acc[i2][j][r] = 0.f;

  int swz = l16 & 7;
  for (int k0 = 0; k0 < H2; k0 += 64) {
#pragma unroll
    for (int R = 0; R < 4; R++) {
      g2l16(ap[R] + k0, As + R * 2048 + tid * 8);
      g2l16(bp[R] + k0, Bs + R * 2048 + tid * 8);
    }
    __syncthreads();
#pragma unroll
    for (int kk = 0; kk < 2; kk++) {
      bf16x8 af[4], bfr[4];
      int q = kk * 4 + quad;
#pragma unroll
      for (int mi = 0; mi < 4; mi++)
        af[mi] = *(const bf16x8*)(As + (wr * 64 + mi * 16 + l16) * 64 + ((q ^ swz) * 8));
#pragma unroll
      for (int ni = 0; ni < 4; ni++)
        bfr[ni] = *(const bf16x8*)(Bs + (wc * 64 + ni * 16 + l16) * 64 + ((q ^ swz) * 8));
#pragma unroll
      for (int mi = 0; mi < 4; mi++)
#pragma unroll
        for (int ni = 0; ni < 4; ni++)
          acc[mi][ni] = __builtin_amdgcn_mfma_f32_16x16x32_bf16(af[mi], bfr[ni], acc[mi][ni], 0, 0, 0);
    }
    __syncthreads();
  }

  // epilogue: plain bf16 stores in slot order (no atomics)
#pragma unroll
  for (int mi = 0; mi < 4; mi++) {
    int rbase = wr * 64 + mi * 16 + quad * 4;
#pragma unroll
    for (int r = 0; r < 4; r++) {
      int rr = m0 + rbase + r;
      if (rr < cnt) {
        size_t yo = (size_t)(base + rr) * H_DIM + nt * 128 + wc * 64 + l16;
#pragma unroll
        for (int ni = 0; ni < 4; ni++)
          y[yo + ni * 16] = f32_to_bf16(acc[mi][ni][r]);
      }
    }
  }
}

// ---------------- Combine: out[t] = g0*y[slot0(t)] + g1*y[slot1(t)]
__global__ __launch_bounds__(256) void combine_kernel(
    const u16* __restrict__ y, const int* __restrict__ tope,
    const float2* __restrict__ gate2, const int2* __restrict__ pos2,
    const int* __restrict__ counts, float* __restrict__ out) {
  int t = blockIdx.x;
  int pk = tope[t];
  int e0 = pk & 0xff, e1 = (pk >> 8) & 0xff;
  float2 g = gate2[t];
  int2 p = pos2[t];
  int hb0 = prefix_base(counts, e0);
  int hb1 = prefix_base(counts, e1);
  size_t s0 = (size_t)(hb0 + p.x) * H_DIM + threadIdx.x * 4;
  size_t s1 = (size_t)(hb1 + p.y) * H_DIM + threadIdx.x * 4;
  ushort4 a = *(const ushort4*)(y + s0);
  ushort4 b = *(const ushort4*)(y + s1);
  float4 o;
  o.x = g.x * bf2f(a.x) + g.y * bf2f(b.x);
  o.y = g.x * bf2f(a.y) + g.y * bf2f(b.y);
  o.z = g.x * bf2f(a.z) + g.y * bf2f(b.z);
  o.w = g.x * bf2f(a.w) + g.y * bf2f(b.w);
  *(float4*)(out + (size_t)t * H_DIM + threadIdx.x * 4) = o;
}

extern "C" void kernel_launch(void* const* d_in, const int* in_sizes, int n_in,
                              void* d_out, int out_size, void* d_ws, size_t ws_size,
                              hipStream_t stream) {
  const float* x  = (const float*)d_in[0];
  const float* rw = (const float*)d_in[1];
  const float* w1 = (const float*)d_in[2];
  const float* w2 = (const float*)d_in[3];
  float* out = (float*)d_out;

  // ws layout (bytes), total ~151.5 MB. y aliases w1b (dead after g1).
  char* ws = (char*)d_ws;
  u16* xb       = (u16*)(ws);                        // 16,777,216
  u16* w1b      = (u16*)(ws + 16777216);             // 33,554,432
  u16* y        = (u16*)(ws + 16777216);             // alias of w1b
  u16* w2b      = (u16*)(ws + 50331648);             // 33,554,432
  u16* h        = (u16*)(ws + 83886080);             // 67,108,864
  int* tok_list = (int*)(ws + 150994944);            // 262,144
  int* tope     = (int*)(ws + 151257088);            // 32,768
  float2* gate2 = (float2*)(ws + 151289856);         // 65,536
  int2* pos2    = (int2*)(ws + 151355392);           // 65,536
  int* counts   = (int*)(ws + 151420928);            // 32

  hipMemsetAsync(counts, 0, 32, stream);
  router_kernel<<<T_TOK / 4 + 1536, 256, 0, stream>>>(x, rw, w1, xb, w1b, tope, gate2);
  build_kernel<<<T_TOK / 256, 256, 0, stream>>>(tope, counts, tok_list, pos2);
  g1_kernel<<<1536 + 16 * 512, 256, 0, stream>>>(xb, w1b, w2, w2b, h, tok_list, counts);
  g2_kernel<<<8 * 512, 256, 0, stream>>>(h, w2b, y, counts);
  combine_kernel<<<T_TOK, 256, 0, stream>>>(y, tope, gate2, pos2, counts, out);
}

// Round 7
// 404.534 us; speedup vs baseline: 1.2627x; 1.2627x over previous
//
#include <hip/hip_runtime.h>
#include <stdint.h>
#include <math.h>

// Problem constants (B=4,S=2048 -> T=8192; H=1024; 2H=2048; E=8; K=2)
#define T_TOK 8192
#define H_DIM 1024
#define H2    2048
#define NE    8

typedef unsigned short u16;
typedef __attribute__((ext_vector_type(8))) short bf16x8;   // 8 bf16 in 4 VGPRs
typedef __attribute__((ext_vector_type(4))) float f32x4;    // MFMA 16x16 C/D

__device__ __forceinline__ u16 f32_to_bf16(float f) {
  union { float f; unsigned u; } c; c.f = f;
  unsigned u = c.u + 0x7fffu + ((c.u >> 16) & 1u);  // RNE
  return (u16)(u >> 16);
}
__device__ __forceinline__ float bf2f(u16 v) {
  union { unsigned u; float f; } c; c.u = (unsigned)v << 16; return c.f;
}

// fast gelu (tanh form), |err| vs exact erf-gelu <= ~1e-3 (R4/R5: absmax
// unchanged at 1.56e-2 vs threshold 4.9e-2)
__device__ __forceinline__ float fast_gelu(float v) {
  float u = v * v;
  float z2 = v * fmaf(u, 0.1029437f, 2.3022078f);
  float e = __builtin_amdgcn_exp2f(z2);
  float r = __builtin_amdgcn_rcpf(1.0f + e);
  return v - v * r;
}

// async global->LDS, 16B per lane. LDS dest is wave-uniform base + lane*16;
// global address is per-lane (exploited for the XOR bank swizzle).
__device__ __forceinline__ void g2l16(const void* g, void* l) {
  __builtin_amdgcn_global_load_lds(
      (const __attribute__((address_space(1))) unsigned*)g,
      (__attribute__((address_space(3))) unsigned*)l, 16, 0, 0);
}

// exclusive prefix of 8 counts, computed per-block (replaces prefix kernel;
// R6-proven)
__device__ __forceinline__ int prefix_base(const int* counts, int e) {
  int b = 0;
#pragma unroll
  for (int j = 0; j < NE; j++) b += (j < e) ? counts[j] : 0;
  return b;
}

// ---------------- Prep: router (blocks 0..2047) + w1/w2 cvt (blocks
// 2048..8191). Heterogeneous fusion: VALU-bound routing overlaps HBM-bound
// conversion (R3: saved 33us vs split). Also zeroes counts (replaces the
// memset node; build only runs after prep completes).
__global__ __launch_bounds__(256) void prep_kernel(
    const float* __restrict__ x, const float* __restrict__ rw,
    const float* __restrict__ w1, const float* __restrict__ w2,
    u16* __restrict__ xb, u16* __restrict__ w1b, u16* __restrict__ w2b,
    int* __restrict__ tope, float2* __restrict__ gate2,
    int* __restrict__ counts) {
  int blk = blockIdx.x;
  if (blk < T_TOK / 4) {
    // ---- router: one wave per token, fp64 logits (exact products -> ranking
    // matches reference top-k)
    int wave = threadIdx.x >> 6;
    int lane = threadIdx.x & 63;
    int t = blk * 4 + wave;
    const float4* x4 = (const float4*)(x + (size_t)t * H_DIM);
    const float4* rw4 = (const float4*)rw;
    u16* xbrow = xb + (size_t)t * H_DIM;

    double acc[NE];
#pragma unroll
    for (int e = 0; e < NE; e++) acc[e] = 0.0;
#pragma unroll
    for (int i = 0; i < 4; i++) {
      int c = lane + 64 * i;
      float4 xv = x4[c];
      ushort4 bv = make_ushort4(f32_to_bf16(xv.x), f32_to_bf16(xv.y),
                                f32_to_bf16(xv.z), f32_to_bf16(xv.w));
      *(ushort4*)(xbrow + c * 4) = bv;
#pragma unroll
      for (int e = 0; e < NE; e++) {
        float4 wv = rw4[e * 256 + c];
        acc[e] += (double)xv.x * wv.x + (double)xv.y * wv.y +
                  (double)xv.z * wv.z + (double)xv.w * wv.w;
      }
    }
#pragma unroll
    for (int off = 32; off >= 1; off >>= 1)
#pragma unroll
      for (int e = 0; e < NE; e++) acc[e] += __shfl_xor(acc[e], off, 64);

    if (lane == 0) {
      int e0 = 0; double v0 = acc[0];
#pragma unroll
      for (int e = 1; e < NE; e++) if (acc[e] > v0) { v0 = acc[e]; e0 = e; }
      int e1 = -1; double v1 = -1e300;
#pragma unroll
      for (int e = 0; e < NE; e++) if (e != e0 && acc[e] > v1) { v1 = acc[e]; e1 = e; }
      double ex = exp(v1 - v0);
      tope[t] = e0 | (e1 << 8);
      gate2[t] = make_float2((float)(1.0 / (1.0 + ex)), (float)(ex / (1.0 + ex)));
    }
  } else {
    // ---- weight cvt: 3072 blocks for w1, 3072 for w2 (2x R5 parallelism)
    int cb = blk - T_TOK / 4;
    if (cb == 0 && threadIdx.x < NE) counts[threadIdx.x] = 0;  // replaces memset
    const float* src; u16* dst;
    if (cb < 3072) { src = w1; dst = w1b; }
    else           { src = w2; dst = w2b; cb -= 3072; }
    const int n4 = NE * H2 * H_DIM / 4;       // 4,194,304 float4s
    const int stride = 3072 * 256;
    const float4* s4 = (const float4*)src;
    for (int i = cb * 256 + threadIdx.x; i < n4; i += stride) {
      float4 v = s4[i];
      *(ushort4*)(dst + (size_t)i * 4) = make_ushort4(
          f32_to_bf16(v.x), f32_to_bf16(v.y), f32_to_bf16(v.z), f32_to_bf16(v.w));
    }
  }
}

// ---------------- Build expert lists: counting sort over 8 bins.
// Per-wave ballot ranks, LDS wave-prefix, ONE atomic per (block,expert).
__global__ __launch_bounds__(256) void build_kernel(
    const int* __restrict__ tope, int* __restrict__ counts,
    int* __restrict__ tok_list, int2* __restrict__ pos2) {
  __shared__ int cts[4][NE];
  __shared__ int gbase[NE];
  int tid = threadIdx.x, lane = tid & 63, w = tid >> 6;
  int t = blockIdx.x * 256 + tid;
  int pk = tope[t];
  int e0 = pk & 0xff, e1 = (pk >> 8) & 0xff;
  unsigned long long lt = ((unsigned long long)1 << lane) - 1;

  int r0 = 0, r1 = 0;
#pragma unroll
  for (int e = 0; e < NE; e++) {
    unsigned long long b0 = __ballot(e0 == e);
    unsigned long long b1 = __ballot(e1 == e);
    int n0 = __popcll(b0), n1 = __popcll(b1);
    if (e0 == e) r0 = __popcll(b0 & lt);
    if (e1 == e) r1 = n0 + __popcll(b1 & lt);
    if (lane == 0) cts[w][e] = n0 + n1;
  }
  __syncthreads();
  if (tid < NE) {
    int bt = cts[0][tid] + cts[1][tid] + cts[2][tid] + cts[3][tid];
    gbase[tid] = atomicAdd(&counts[tid], bt);
  }
  __syncthreads();
  int off0 = gbase[e0] + r0;
  int off1 = gbase[e1] + r1;
#pragma unroll
  for (int wp = 0; wp < 4; wp++) {
    if (wp < w) { off0 += cts[wp][e0]; off1 += cts[wp][e1]; }
  }
  tok_list[e0 * T_TOK + off0] = t;
  tok_list[e1 * T_TOK + off1] = t;
  pos2[t] = make_int2(off0, off1);
}

// ---------------- G1: h[base+i] = gelu( x[tok_i] @ w1[e]^T )
// 128x128 tile, BK=64, XOR bank swizzle (R5: conflicts = 0, 110us).
// Block order = R5's (e,mt,nt) row-major: consecutive blocks share the
// A-tile -> temporal L2 locality (R6's XCD pinning broke this: +36MB FETCH).
__global__ __launch_bounds__(256) void g1_kernel(
    const u16* __restrict__ xb, const u16* __restrict__ w1b,
    u16* __restrict__ h, const int* __restrict__ tok_list,
    const int* __restrict__ counts) {
  const int NT = H2 / 128;  // 16
  int e = blockIdx.x / (64 * NT);
  int rem = blockIdx.x % (64 * NT);
  int mt = rem / NT, nt = rem % NT;
  int cnt = counts[e];
  int m0 = mt * 128;
  if (m0 >= cnt) return;
  int base = prefix_base(counts, e);

  __shared__ u16 As[128 * 64];   // 16 KB
  __shared__ u16 Bs[128 * 64];   // 16 KB

  int tid = threadIdx.x;
  int lane = tid & 63, wave = tid >> 6;
  int wr = wave >> 1, wc = wave & 1;
  int quad = lane >> 4, l16 = lane & 15;
  int srow = tid >> 3;                         // staging: 32 rows/round
  int cg = (tid & 7) ^ (srow & 7);             // XOR-swizzled fetch chunk

  const u16* w1e = w1b + (size_t)e * H2 * H_DIM;
  const u16* ap[4]; const u16* bp[4];
#pragma unroll
  for (int R = 0; R < 4; R++) {
    int r = m0 + R * 32 + srow; if (r > cnt - 1) r = cnt - 1;
    ap[R] = xb + (size_t)tok_list[e * T_TOK + r] * H_DIM + cg * 8;
    bp[R] = w1e + (size_t)(nt * 128 + R * 32 + srow) * H_DIM + cg * 8;
  }

  f32x4 acc[4][4];
#pragma unroll
  for (int i = 0; i < 4; i++)
#pragma unroll
    for (int j = 0; j < 4; j++)
#pragma unroll
      for (int r = 0; r < 4; r++) acc[i][j][r] = 0.f;

  int swz = l16 & 7;
  for (int k0 = 0; k0 < H_DIM; k0 += 64) {
#pragma unroll
    for (int R = 0; R < 4; R++) {
      g2l16(ap[R] + k0, As + R * 2048 + tid * 8);
      g2l16(bp[R] + k0, Bs + R * 2048 + tid * 8);
    }
    __syncthreads();
#pragma unroll
    for (int kk = 0; kk < 2; kk++) {
      bf16x8 af[4], bfr[4];
      int q = kk * 4 + quad;
#pragma unroll
      for (int mi = 0; mi < 4; mi++)
        af[mi] = *(const bf16x8*)(As + (wr * 64 + mi * 16 + l16) * 64 + ((q ^ swz) * 8));
#pragma unroll
      for (int ni = 0; ni < 4; ni++)
        bfr[ni] = *(const bf16x8*)(Bs + (wc * 64 + ni * 16 + l16) * 64 + ((q ^ swz) * 8));
#pragma unroll
      for (int mi = 0; mi < 4; mi++)
#pragma unroll
        for (int ni = 0; ni < 4; ni++)
          acc[mi][ni] = __builtin_amdgcn_mfma_f32_16x16x32_bf16(af[mi], bfr[ni], acc[mi][ni], 0, 0, 0);
    }
    __syncthreads();
  }

  // epilogue: fast gelu, store bf16; C/D layout col=lane&15, row=quad*4+reg
#pragma unroll
  for (int mi = 0; mi < 4; mi++) {
    int rbase = wr * 64 + mi * 16 + quad * 4;
#pragma unroll
    for (int r = 0; r < 4; r++) {
      int rr = m0 + rbase + r;
      if (rr < cnt) {
        size_t ho = (size_t)(base + rr) * H2 + nt * 128 + wc * 64 + l16;
#pragma unroll
        for (int ni = 0; ni < 4; ni++)
          h[ho + ni * 16] = f32_to_bf16(fast_gelu(acc[mi][ni][r]));
      }
    }
  }
}

// ---------------- G2: y[base+i] = h[base+i] @ w2[e]^T (BK=64, swizzled,
// R5 block order)
__global__ __launch_bounds__(256) void g2_kernel(
    const u16* __restrict__ h, const u16* __restrict__ w2b,
    u16* __restrict__ y, const int* __restrict__ counts) {
  const int NT = H_DIM / 128;  // 8
  int e = blockIdx.x / (64 * NT);
  int rem = blockIdx.x % (64 * NT);
  int mt = rem / NT, nt = rem % NT;
  int cnt = counts[e];
  int m0 = mt * 128;
  if (m0 >= cnt) return;
  int base = prefix_base(counts, e);

  __shared__ u16 As[128 * 64];
  __shared__ u16 Bs[128 * 64];

  int tid = threadIdx.x;
  int lane = tid & 63, wave = tid >> 6;
  int wr = wave >> 1, wc = wave & 1;
  int quad = lane >> 4, l16 = lane & 15;
  int srow = tid >> 3;
  int cg = (tid & 7) ^ (srow & 7);

  const u16* w2e = w2b + (size_t)e * H_DIM * H2;
  const u16* ap[4]; const u16* bp[4];
#pragma unroll
  for (int R = 0; R < 4; R++) {
    int r = m0 + R * 32 + srow; if (r > cnt - 1) r = cnt - 1;
    ap[R] = h + (size_t)(base + r) * H2 + cg * 8;
    bp[R] = w2e + (size_t)(nt * 128 + R * 32 + srow) * H2 + cg * 8;
  }

  f32x4 acc[4][4];
#pragma unroll
  for (int i = 0; i < 4; i++)
#pragma unroll
    for (int j = 0; j < 4; j++)
#pragma unroll
      for (int r = 0; r < 4; r++) acc[i][j][r] = 0.f;

  int swz = l16 & 7;
  for (int k0 = 0; k0 < H2; k0 += 64) {
#pragma unroll
    for (int R = 0; R < 4; R++) {
      g2l16(ap[R] + k0, As + R * 2048 + tid * 8);
      g2l16(bp[R] + k0, Bs + R * 2048 + tid * 8);
    }
    __syncthreads();
#pragma unroll
    for (int kk = 0; kk < 2; kk++) {
      bf16x8 af[4], bfr[4];
      int q = kk * 4 + quad;
#pragma unroll
      for (int mi = 0; mi < 4; mi++)
        af[mi] = *(const bf16x8*)(As + (wr * 64 + mi * 16 + l16) * 64 + ((q ^ swz) * 8));
#pragma unroll
      for (int ni = 0; ni < 4; ni++)
        bfr[ni] = *(const bf16x8*)(Bs + (wc * 64 + ni * 16 + l16) * 64 + ((q ^ swz) * 8));
#pragma unroll
      for (int mi = 0; mi < 4; mi++)
#pragma unroll
        for (int ni = 0; ni < 4; ni++)
          acc[mi][ni] = __builtin_amdgcn_mfma_f32_16x16x32_bf16(af[mi], bfr[ni], acc[mi][ni], 0, 0, 0);
    }
    __syncthreads();
  }

  // epilogue: plain bf16 stores in slot order (no atomics)
#pragma unroll
  for (int mi = 0; mi < 4; mi++) {
    int rbase = wr * 64 + mi * 16 + quad * 4;
#pragma unroll
    for (int r = 0; r < 4; r++) {
      int rr = m0 + rbase + r;
      if (rr < cnt) {
        size_t yo = (size_t)(base + rr) * H_DIM + nt * 128 + wc * 64 + l16;
#pragma unroll
        for (int ni = 0; ni < 4; ni++)
          y[yo + ni * 16] = f32_to_bf16(acc[mi][ni][r]);
      }
    }
  }
}

// ---------------- Combine: out[t] = g0*y[slot0(t)] + g1*y[slot1(t)]
// Writes every output element -> no d_out memset needed.
__global__ __launch_bounds__(256) void combine_kernel(
    const u16* __restrict__ y, const int* __restrict__ tope,
    const float2* __restrict__ gate2, const int2* __restrict__ pos2,
    const int* __restrict__ counts, float* __restrict__ out) {
  int t = blockIdx.x;
  int pk = tope[t];
  int e0 = pk & 0xff, e1 = (pk >> 8) & 0xff;
  float2 g = gate2[t];
  int2 p = pos2[t];
  int hb0 = prefix_base(counts, e0);
  int hb1 = prefix_base(counts, e1);
  size_t s0 = (size_t)(hb0 + p.x) * H_DIM + threadIdx.x * 4;
  size_t s1 = (size_t)(hb1 + p.y) * H_DIM + threadIdx.x * 4;
  ushort4 a = *(const ushort4*)(y + s0);
  ushort4 b = *(const ushort4*)(y + s1);
  float4 o;
  o.x = g.x * bf2f(a.x) + g.y * bf2f(b.x);
  o.y = g.x * bf2f(a.y) + g.y * bf2f(b.y);
  o.z = g.x * bf2f(a.z) + g.y * bf2f(b.z);
  o.w = g.x * bf2f(a.w) + g.y * bf2f(b.w);
  *(float4*)(out + (size_t)t * H_DIM + threadIdx.x * 4) = o;
}

extern "C" void kernel_launch(void* const* d_in, const int* in_sizes, int n_in,
                              void* d_out, int out_size, void* d_ws, size_t ws_size,
                              hipStream_t stream) {
  const float* x  = (const float*)d_in[0];
  const float* rw = (const float*)d_in[1];
  const float* w1 = (const float*)d_in[2];
  const float* w2 = (const float*)d_in[3];
  float* out = (float*)d_out;

  // ws layout (bytes), total ~151.5 MB. y aliases w1b (dead after g1).
  char* ws = (char*)d_ws;
  u16* xb       = (u16*)(ws);                        // 16,777,216
  u16* w1b      = (u16*)(ws + 16777216);             // 33,554,432
  u16* y        = (u16*)(ws + 16777216);             // alias of w1b
  u16* w2b      = (u16*)(ws + 50331648);             // 33,554,432
  u16* h        = (u16*)(ws + 83886080);             // 67,108,864
  int* tok_list = (int*)(ws + 150994944);            // 262,144
  int* tope     = (int*)(ws + 151257088);            // 32,768
  float2* gate2 = (float2*)(ws + 151289856);         // 65,536
  int2* pos2    = (int2*)(ws + 151355392);           // 65,536
  int* counts   = (int*)(ws + 151420928);            // 32

  // 5 graph nodes (was 7): memset folded into prep, prefix into consumers.
  prep_kernel<<<T_TOK / 4 + 6144, 256, 0, stream>>>(x, rw, w1, w2, xb, w1b, w2b,
                                                    tope, gate2, counts);
  build_kernel<<<T_TOK / 256, 256, 0, stream>>>(tope, counts, tok_list, pos2);
  g1_kernel<<<NE * 64 * (H2 / 128), 256, 0, stream>>>(xb, w1b, h, tok_list, counts);
  g2_kernel<<<NE * 64 * (H_DIM / 128), 256, 0, stream>>>(h, w2b, y, counts);
  combine_kernel<<<T_TOK, 256, 0, stream>>>(y, tope, gate2, pos2, counts, out);
}